// Round 1
// baseline (3577.480 us; speedup 1.0000x reference)
//
#include <hip/hip_runtime.h>
#include <math.h>

#define S_LEN 2048
#define D_DIM 1024
#define NH 16
#define DH 64
#define NPOS 512   // 2*SPAN

// ---------------------------------------------------------------------------
// Kernel A: C(M x 1024) = X(M x 1024) @ W(1024 x 1024) + bias, output written
// head-split: out[(h*M + row)*64 + (n&63)] where h = n>>6.
// 128x128 tile, 256 threads, 8x8 per thread, K-step 16. fp32 vector FMA.
// ---------------------------------------------------------------------------
__global__ __launch_bounds__(256) void proj_gemm(
    const float* __restrict__ X, const float* __restrict__ W,
    const float* __restrict__ bias, float* __restrict__ outp, int M) {
  __shared__ float xt[16][132];   // X tile transposed [k][row], pad->132
  __shared__ float wt[16][128];   // W tile straight  [k][col]
  const int tid = threadIdx.x;
  const int br = blockIdx.y, bc = blockIdx.x;
  const int r0 = (tid >> 4) * 8, c0 = (tid & 15) * 8;
  float acc[8][8];
  #pragma unroll
  for (int i = 0; i < 8; i++)
    #pragma unroll
    for (int j = 0; j < 8; j++) acc[i][j] = 0.f;

  const float* Xb = X + (size_t)br * 128 * D_DIM;
  const float* Wb = W + bc * 128;

  for (int k0 = 0; k0 < D_DIM; k0 += 16) {
    __syncthreads();
    #pragma unroll
    for (int i = 0; i < 2; i++) {
      int slot = tid + i * 256;            // 0..511
      int row = slot >> 2;                 // 0..127
      int kc = (slot & 3) * 4;             // 0,4,8,12
      float4 xv = *(const float4*)(Xb + (size_t)row * D_DIM + k0 + kc);
      xt[kc + 0][row] = xv.x; xt[kc + 1][row] = xv.y;
      xt[kc + 2][row] = xv.z; xt[kc + 3][row] = xv.w;
      int kr = slot >> 5;                  // 0..15
      int wc = (slot & 31) * 4;            // 0..124
      *(float4*)&wt[kr][wc] = *(const float4*)(Wb + (size_t)(k0 + kr) * D_DIM + wc);
    }
    __syncthreads();
    #pragma unroll
    for (int kk = 0; kk < 16; kk++) {
      float a[8], b[8];
      *(float4*)&a[0] = *(const float4*)&xt[kk][r0];
      *(float4*)&a[4] = *(const float4*)&xt[kk][r0 + 4];
      *(float4*)&b[0] = *(const float4*)&wt[kk][c0];
      *(float4*)&b[4] = *(const float4*)&wt[kk][c0 + 4];
      #pragma unroll
      for (int ii = 0; ii < 8; ii++)
        #pragma unroll
        for (int jj = 0; jj < 8; jj++)
          acc[ii][jj] = fmaf(a[ii], b[jj], acc[ii][jj]);
    }
  }

  const int n0 = bc * 128 + c0;          // 8 consecutive cols, same head block
  const int h = n0 >> 6, iw = n0 & 63;
  float bvals[8];
  #pragma unroll
  for (int jj = 0; jj < 8; jj++) bvals[jj] = bias[n0 + jj];
  #pragma unroll
  for (int ii = 0; ii < 8; ii++) {
    size_t row = (size_t)br * 128 + r0 + ii;
    float ov[8];
    #pragma unroll
    for (int jj = 0; jj < 8; jj++) ov[jj] = acc[ii][jj] + bvals[jj];
    float* dst = outp + ((size_t)h * M + row) * 64 + iw;
    *(float4*)dst = *(float4*)&ov[0];
    *(float4*)(dst + 4) = *(float4*)&ov[4];
  }
}

// ---------------------------------------------------------------------------
// Kernel B: per-head C(2048 x 512) = A(2048 x 64) @ Bm(512 x 64)^T * inv_scale
// z < 16:  A=q[h],  Bm=pos_k[h] -> c2p ;  z >= 16: A=k[h], Bm=pos_q[h] -> p2c
// ---------------------------------------------------------------------------
__global__ __launch_bounds__(256) void rel_gemm(
    const float* __restrict__ q_ws, const float* __restrict__ k_ws,
    const float* __restrict__ pk_ws, const float* __restrict__ pq_ws,
    float* __restrict__ c2p, float* __restrict__ p2c, float inv_scale) {
  __shared__ float at[16][132];
  __shared__ float bt[16][132];
  const int tid = threadIdx.x;
  const int h = blockIdx.z & 15;
  const int which = blockIdx.z >> 4;
  const float* A = (which ? k_ws : q_ws) + (size_t)h * S_LEN * DH;
  const float* Bm = (which ? pq_ws : pk_ws) + (size_t)h * NPOS * DH;
  float* C = (which ? p2c : c2p) + (size_t)h * S_LEN * NPOS;
  const int br = blockIdx.y, bc = blockIdx.x;
  const int r0 = (tid >> 4) * 8, c0 = (tid & 15) * 8;
  float acc[8][8];
  #pragma unroll
  for (int i = 0; i < 8; i++)
    #pragma unroll
    for (int j = 0; j < 8; j++) acc[i][j] = 0.f;

  for (int k0 = 0; k0 < DH; k0 += 16) {
    __syncthreads();
    #pragma unroll
    for (int i = 0; i < 2; i++) {
      int slot = tid + i * 256;
      int row = slot >> 2;
      int kc = (slot & 3) * 4;
      float4 av = *(const float4*)(A + (size_t)(br * 128 + row) * DH + k0 + kc);
      at[kc + 0][row] = av.x; at[kc + 1][row] = av.y;
      at[kc + 2][row] = av.z; at[kc + 3][row] = av.w;
      float4 bv = *(const float4*)(Bm + (size_t)(bc * 128 + row) * DH + k0 + kc);
      bt[kc + 0][row] = bv.x; bt[kc + 1][row] = bv.y;
      bt[kc + 2][row] = bv.z; bt[kc + 3][row] = bv.w;
    }
    __syncthreads();
    #pragma unroll
    for (int kk = 0; kk < 16; kk++) {
      float a[8], b[8];
      *(float4*)&a[0] = *(const float4*)&at[kk][r0];
      *(float4*)&a[4] = *(const float4*)&at[kk][r0 + 4];
      *(float4*)&b[0] = *(const float4*)&bt[kk][c0];
      *(float4*)&b[4] = *(const float4*)&bt[kk][c0 + 4];
      #pragma unroll
      for (int ii = 0; ii < 8; ii++)
        #pragma unroll
        for (int jj = 0; jj < 8; jj++)
          acc[ii][jj] = fmaf(a[ii], b[jj], acc[ii][jj]);
    }
  }
  #pragma unroll
  for (int ii = 0; ii < 8; ii++) {
    size_t row = (size_t)br * 128 + r0 + ii;
    float ov[8];
    #pragma unroll
    for (int jj = 0; jj < 8; jj++) ov[jj] = acc[ii][jj] * inv_scale;
    float* dst = C + row * NPOS + bc * 128 + c0;
    *(float4*)dst = *(float4*)&ov[0];
    *(float4*)(dst + 4) = *(float4*)&ov[4];
  }
}

// ---------------------------------------------------------------------------
// Kernel C: fused flash attention with gathered disentangled biases.
// Block = (head h, 64-row q tile). 256 threads, thread (r4,c4) owns a 4x4
// score/output patch. kT buffer is reused to hold P^T between QK and PV.
// ---------------------------------------------------------------------------
__global__ __launch_bounds__(256) void attn_kernel(
    const float* __restrict__ q_ws, const float* __restrict__ k_ws,
    const float* __restrict__ v_ws, const float* __restrict__ c2p,
    const float* __restrict__ p2c, const int* __restrict__ ids,
    const int* __restrict__ ids_t, float* __restrict__ outp, float inv_scale) {
  __shared__ float qT[64][68];    // q tile transposed [d][s]
  __shared__ float kT[64][68];    // k tile transposed [d][t]; reused as pT[t][r]
  __shared__ float vS[64][64];    // v tile straight [t][d]
  const int tid = threadIdx.x;
  const int h = blockIdx.y;
  const int s0 = blockIdx.x * 64;
  const int r4 = tid >> 4, c4 = tid & 15;
  const int r0 = r4 * 4, c0 = c4 * 4;

  const float* qb = q_ws + ((size_t)h * S_LEN + s0) * DH;
  const float* kb = k_ws + (size_t)h * S_LEN * DH;
  const float* vb = v_ws + (size_t)h * S_LEN * DH;

  // load q tile transposed
  #pragma unroll
  for (int i = 0; i < 4; i++) {
    int slot = tid + i * 256;          // 0..1023
    int s = slot >> 4;                 // 0..63
    int dc = (slot & 15) * 4;
    float4 qv = *(const float4*)(qb + (size_t)s * DH + dc);
    qT[dc + 0][s] = qv.x; qT[dc + 1][s] = qv.y;
    qT[dc + 2][s] = qv.z; qT[dc + 3][s] = qv.w;
  }

  float m[4], l[4], o[4][4];
  #pragma unroll
  for (int ii = 0; ii < 4; ii++) {
    m[ii] = -INFINITY; l[ii] = 0.f;
    #pragma unroll
    for (int jj = 0; jj < 4; jj++) o[ii][jj] = 0.f;
  }

  for (int kt = 0; kt < S_LEN / 64; kt++) {
    const int t0 = kt * 64;
    __syncthreads();   // prior PV reads of kT/vS done (noop first iter)
    #pragma unroll
    for (int i = 0; i < 4; i++) {
      int slot = tid + i * 256;
      int t = slot >> 4;
      int dc = (slot & 15) * 4;
      float4 kv = *(const float4*)(kb + (size_t)(t0 + t) * DH + dc);
      kT[dc + 0][t] = kv.x; kT[dc + 1][t] = kv.y;
      kT[dc + 2][t] = kv.z; kT[dc + 3][t] = kv.w;
      float4 vv = *(const float4*)(vb + (size_t)(t0 + t) * DH + dc);
      *(float4*)&vS[t][dc] = vv;
    }
    __syncthreads();

    // QK^T mini-GEMM: sc[4][4]
    float sc[4][4];
    #pragma unroll
    for (int ii = 0; ii < 4; ii++)
      #pragma unroll
      for (int jj = 0; jj < 4; jj++) sc[ii][jj] = 0.f;
    #pragma unroll 8
    for (int d = 0; d < 64; d++) {
      float a[4], b[4];
      *(float4*)a = *(const float4*)&qT[d][r0];
      *(float4*)b = *(const float4*)&kT[d][c0];
      #pragma unroll
      for (int ii = 0; ii < 4; ii++)
        #pragma unroll
        for (int jj = 0; jj < 4; jj++)
          sc[ii][jj] = fmaf(a[ii], b[jj], sc[ii][jj]);
    }
    #pragma unroll
    for (int ii = 0; ii < 4; ii++)
      #pragma unroll
      for (int jj = 0; jj < 4; jj++) sc[ii][jj] *= inv_scale;

    // c2p bias: ids[(h*S + s)*S + t], contiguous in t (int4)
    #pragma unroll
    for (int ii = 0; ii < 4; ii++) {
      const size_t s = s0 + r0 + ii;
      int4 iv = *(const int4*)(ids + ((size_t)h * S_LEN + s) * S_LEN + t0 + c0);
      sc[ii][0] += c2p[iv.x]; sc[ii][1] += c2p[iv.y];
      sc[ii][2] += c2p[iv.z]; sc[ii][3] += c2p[iv.w];
    }
    // p2c bias (transposed gather): ids_t[(h*S + t)*S + s], contiguous in s
    #pragma unroll
    for (int jj = 0; jj < 4; jj++) {
      const size_t t = t0 + c0 + jj;
      int4 iv = *(const int4*)(ids_t + ((size_t)h * S_LEN + t) * S_LEN + s0 + r0);
      sc[0][jj] += p2c[iv.x]; sc[1][jj] += p2c[iv.y];
      sc[2][jj] += p2c[iv.z]; sc[3][jj] += p2c[iv.w];
    }

    // online softmax (rows owned by the 16 lanes sharing r4; reduce over c4)
    #pragma unroll
    for (int ii = 0; ii < 4; ii++) {
      float v = fmaxf(fmaxf(sc[ii][0], sc[ii][1]), fmaxf(sc[ii][2], sc[ii][3]));
      v = fmaxf(v, __shfl_xor(v, 1));
      v = fmaxf(v, __shfl_xor(v, 2));
      v = fmaxf(v, __shfl_xor(v, 4));
      v = fmaxf(v, __shfl_xor(v, 8));
      float mn = fmaxf(m[ii], v);
      float alpha = __expf(m[ii] - mn);
      m[ii] = mn;
      float rs = 0.f;
      #pragma unroll
      for (int jj = 0; jj < 4; jj++) {
        sc[ii][jj] = __expf(sc[ii][jj] - mn);
        rs += sc[ii][jj];
      }
      rs += __shfl_xor(rs, 1);
      rs += __shfl_xor(rs, 2);
      rs += __shfl_xor(rs, 4);
      rs += __shfl_xor(rs, 8);
      l[ii] = l[ii] * alpha + rs;
      #pragma unroll
      for (int jj = 0; jj < 4; jj++) o[ii][jj] *= alpha;
    }

    __syncthreads();   // all QK reads of kT done -> safe to overwrite with pT
    #pragma unroll
    for (int jj = 0; jj < 4; jj++) {
      float pv[4] = {sc[0][jj], sc[1][jj], sc[2][jj], sc[3][jj]};
      *(float4*)&kT[c0 + jj][r0] = *(float4*)pv;   // pT[t][r]
    }
    __syncthreads();

    // PV mini-GEMM: o[r][d] += sum_t pT[t][r] * vS[t][d]
    #pragma unroll 8
    for (int t = 0; t < 64; t++) {
      float a[4], b[4];
      *(float4*)a = *(const float4*)&kT[t][r0];
      *(float4*)b = *(const float4*)&vS[t][c0];
      #pragma unroll
      for (int ii = 0; ii < 4; ii++)
        #pragma unroll
        for (int jj = 0; jj < 4; jj++)
          o[ii][jj] = fmaf(a[ii], b[jj], o[ii][jj]);
    }
  }

  // epilogue: out (B,S,D) with D = h*64 + d
  #pragma unroll
  for (int ii = 0; ii < 4; ii++) {
    float inv_l = 1.0f / l[ii];
    float ov[4];
    #pragma unroll
    for (int jj = 0; jj < 4; jj++) ov[jj] = o[ii][jj] * inv_l;
    float* dst = outp + (size_t)(s0 + r0 + ii) * D_DIM + h * DH + c0;
    *(float4*)dst = *(float4*)ov;
  }
}

// ---------------------------------------------------------------------------
extern "C" void kernel_launch(void* const* d_in, const int* in_sizes, int n_in,
                              void* d_out, int out_size, void* d_ws, size_t ws_size,
                              hipStream_t stream) {
  const float* hs  = (const float*)d_in[0];
  const float* rel = (const float*)d_in[1];
  const float* Wq  = (const float*)d_in[2];
  const float* bq  = (const float*)d_in[3];
  const float* Wk  = (const float*)d_in[4];
  const float* bk  = (const float*)d_in[5];
  const float* Wv  = (const float*)d_in[6];
  const float* bv  = (const float*)d_in[7];
  const int* ids   = (const int*)d_in[8];
  const int* ids_t = (const int*)d_in[9];
  float* outp = (float*)d_out;

  float* ws = (float*)d_ws;
  float* q_ws  = ws;                         // 16*2048*64 = 2097152
  float* k_ws  = q_ws + 2097152;
  float* v_ws  = k_ws + 2097152;
  float* pk_ws = v_ws + 2097152;             // 16*512*64 = 524288
  float* pq_ws = pk_ws + 524288;
  float* c2p_ws = pq_ws + 524288;            // 16*2048*512 = 16777216
  float* p2c_ws = c2p_ws + 16777216;         // total ~156 MB

  const float inv_scale = 1.0f / sqrtf((float)(DH * 3));

  dim3 blk(256);
  proj_gemm<<<dim3(8, 16), blk, 0, stream>>>(hs, Wq, bq, q_ws, S_LEN);
  proj_gemm<<<dim3(8, 16), blk, 0, stream>>>(hs, Wk, bk, k_ws, S_LEN);
  proj_gemm<<<dim3(8, 16), blk, 0, stream>>>(hs, Wv, bv, v_ws, S_LEN);
  proj_gemm<<<dim3(8, 4),  blk, 0, stream>>>(rel, Wk, bk, pk_ws, NPOS);
  proj_gemm<<<dim3(8, 4),  blk, 0, stream>>>(rel, Wq, bq, pq_ws, NPOS);
  rel_gemm<<<dim3(4, 16, 32), blk, 0, stream>>>(q_ws, k_ws, pk_ws, pq_ws,
                                                c2p_ws, p2c_ws, inv_scale);
  attn_kernel<<<dim3(32, 16), blk, 0, stream>>>(q_ws, k_ws, v_ws, c2p_ws,
                                                p2c_ws, ids, ids_t, outp, inv_scale);
}